// Round 8
// baseline (321.360 us; speedup 1.0000x reference)
//
#include <hip/hip_runtime.h>
#include <hip/hip_fp16.h>

#define NN 50000
#define NP 25000
#define NE 800000
#define DD 64
#define NL 4
#define CSR_CAP (NE + 7 * NN + 16)   // padded segments + prefetch slack

// ---- helpers ------------------------------------------------------------

__device__ __forceinline__ ushort f2bf(float f) {
    unsigned u = __float_as_uint(f);
    unsigned r = (u + 0x7fffu + ((u >> 16) & 1u)) >> 16;   // RNE
    return (ushort)r;
}

__device__ __forceinline__ float4 bf4_to_f4(uint a, uint b) {
    float4 r;
    r.x = __uint_as_float(a << 16);
    r.y = __uint_as_float(a & 0xffff0000u);
    r.z = __uint_as_float(b << 16);
    r.w = __uint_as_float(b & 0xffff0000u);
    return r;
}

__device__ __forceinline__ float4 ld_bf16x4(const uint2* p) {
    uint2 q = *p;
    return bf4_to_f4(q.x, q.y);
}

// ---- CSR build ----------------------------------------------------------
// Pass 1: count in-degree AND record each edge's rank within its dst bucket.

__global__ void count_edges_k(const int* __restrict__ dst, int* __restrict__ cnt,
                              int* __restrict__ rank, int E) {
    int e = blockIdx.x * 256 + threadIdx.x;
    if (e < E) rank[e] = atomicAdd(&cnt[dst[e]], 1);
}

// Single-block scan: rowptr = exclusive prefix of PADDED counts (pad to x8),
// plus dinv. 1024 threads x 49 contiguous elements each.
__global__ void scan_all_k(const int* __restrict__ cnt, int* __restrict__ rowptr,
                           float* __restrict__ dinv, int n) {
    __shared__ int tsum[1024];
    int t = threadIdx.x;
    int base = t * 49;
    int s = 0;
    for (int k = 0; k < 49; ++k) {
        int i = base + k;
        if (i < n) s += (cnt[i] + 7) & ~7;
    }
    tsum[t] = s;
    __syncthreads();
    for (int off = 1; off < 1024; off <<= 1) {
        int a = (t >= off) ? tsum[t - off] : 0;
        __syncthreads();
        tsum[t] += a;
        __syncthreads();
    }
    int run = tsum[t] - s;     // exclusive chunk offset
    for (int k = 0; k < 49; ++k) {
        int i = base + k;
        if (i < n) {
            int c = cnt[i];
            rowptr[i] = run;
            run += (c + 7) & ~7;
            dinv[i] = rsqrtf((float)(c + 1));   // +1 self loop
        }
    }
    if (t == 1023) rowptr[n] = run;
}

// csr entry: bits 0..15 = src index (NN < 65536), bits 16..31 = fp16 weight.
// Block range [0,3125): CSR fill (no atomics). [3125,4688): unpool scatter.
__global__ void fill_scatter_k(const int* __restrict__ src, const int* __restrict__ dst,
                               const int* __restrict__ rank, const int* __restrict__ rowptr,
                               const float* __restrict__ dinv, uint* __restrict__ csr,
                               const float4* __restrict__ x4, const int* __restrict__ idx,
                               ushort4* __restrict__ c0) {
    int b = blockIdx.x;
    if (b < 3125) {
        int e = b * 256 + threadIdx.x;   // 3125*256 == NE
        int s = src[e], d = dst[e];
        int p = rowptr[d] + rank[e];
        float w = dinv[s] * dinv[d];
        uint h = (uint)__half_as_ushort(__float2half_rn(w));
        csr[p] = (uint)s | (h << 16);
    } else {
        int i = (b - 3125) * 256 + threadIdx.x;   // NP*16 quads
        if (i >= NP * 16) return;
        int row = i >> 4, q = i & 15;
        float4 v = x4[i];
        ushort4 o;
        o.x = f2bf(v.x); o.y = f2bf(v.y); o.z = f2bf(v.z); o.w = f2bf(v.w);
        c0[(size_t)idx[row] * 16 + q] = o;
    }
}

// ---- GEMM: xw_bf16[50000x64] = cur_bf16[50000x64] @ W[64x64] ------------

__global__ void gemm64_k(const uint2* __restrict__ in2, const float* __restrict__ W,
                         ushort* __restrict__ out) {
    __shared__ float sW[64][64];     // 16 KB
    __shared__ float srow[16][64];   // 4 KB
    int t = threadIdx.x;             // 256 threads
    const float4* W4 = (const float4*)W;
    float4* sW4 = (float4*)sW;
#pragma unroll
    for (int j = 0; j < 4; ++j) sW4[t + 256 * j] = W4[t + 256 * j];
    int r0 = blockIdx.x * 16;
    float4 val = ld_bf16x4(in2 + (size_t)r0 * 16 + t);
    *(float4*)&srow[t >> 4][4 * (t & 15)] = val;
    __syncthreads();
    int r = t >> 4;            // 0..15
    int c4 = (t & 15) * 4;     // 0,4,...,60
    float ax = 0.f, ay = 0.f, az = 0.f, aw = 0.f;
#pragma unroll
    for (int k = 0; k < 64; ++k) {
        float a = srow[r][k];
        float4 w = *(const float4*)&sW[k][c4];
        ax += a * w.x; ay += a * w.y; az += a * w.z; aw += a * w.w;
    }
    ushort4 o;
    o.x = f2bf(ax); o.y = f2bf(ay); o.z = f2bf(az); o.w = f2bf(aw);
    *(ushort4*)&out[(size_t)(r0 + r) * 64 + c4] = o;
}

// ---- fused: aggregate(bf16 gather) + bias + LN + LeakyReLU --------------
// 8 nodes per wave (8-lane octets). Lane l8 holds features 8*l8..8*l8+7.
// Padded CSR: segments are multiples of 8 entries, 16B-aligned; pad entries
// are (src=0, w=0). 8 edges/iter from 2 uint4 loads, next iter's csr
// prefetched while gathers are in flight. No clamps, no tail logic.

__global__ void agg_ln_k(const uint4* __restrict__ xw4, const int* __restrict__ rowptr,
                         const uint* __restrict__ csr, const float* __restrict__ dinv,
                         const float4* __restrict__ bias4, const float4* __restrict__ gamma4,
                         const float4* __restrict__ beta4, uint4* next,
                         const uint4* c1, const uint4* c2, const uint4* c3,
                         float4* outp, int last) {
    int tid = threadIdx.x;
    int l8 = tid & 7;                       // feature octet-chunk 0..7
    int v = blockIdx.x * 32 + (tid >> 3);   // 32 nodes per 256-thread block
    if (v >= NN) return;
    const uint4* csrq = (const uint4*)csr;
    float dv = dinv[v];
    int jb = rowptr[v], je = rowptr[v + 1];   // both multiples of 8
    float4 aLo, aHi;
    {
        uint4 q = xw4[(size_t)v * 8 + l8];   // self loop
        float4 lo = bf4_to_f4(q.x, q.y), hi = bf4_to_f4(q.z, q.w);
        float s = dv * dv;
        aLo.x = s * lo.x; aLo.y = s * lo.y; aLo.z = s * lo.z; aLo.w = s * lo.w;
        aHi.x = s * hi.x; aHi.y = s * hi.y; aHi.z = s * hi.z; aHi.w = s * hi.w;
    }
    uint4 ca = csrq[jb >> 2];        // safe: buffer has slack
    uint4 cb = csrq[(jb >> 2) + 1];
#define WGT(E)  __half2float(__ushort_as_half((ushort)((E) >> 16)))
    for (int j = jb; j < je; j += 8) {
        uint4 na = csrq[(j >> 2) + 2];   // prefetch next 8 entries
        uint4 nb = csrq[(j >> 2) + 3];
        uint4 q0 = xw4[(size_t)(ca.x & 0xffffu) * 8 + l8];
        uint4 q1 = xw4[(size_t)(ca.y & 0xffffu) * 8 + l8];
        uint4 q2 = xw4[(size_t)(ca.z & 0xffffu) * 8 + l8];
        uint4 q3 = xw4[(size_t)(ca.w & 0xffffu) * 8 + l8];
        uint4 q4 = xw4[(size_t)(cb.x & 0xffffu) * 8 + l8];
        uint4 q5 = xw4[(size_t)(cb.y & 0xffffu) * 8 + l8];
        uint4 q6 = xw4[(size_t)(cb.z & 0xffffu) * 8 + l8];
        uint4 q7 = xw4[(size_t)(cb.w & 0xffffu) * 8 + l8];
        float w0 = WGT(ca.x), w1 = WGT(ca.y), w2 = WGT(ca.z), w3 = WGT(ca.w);
        float w4 = WGT(cb.x), w5 = WGT(cb.y), w6 = WGT(cb.z), w7 = WGT(cb.w);
#define ACC(Q, W) { \
        float4 lo = bf4_to_f4(Q.x, Q.y), hi = bf4_to_f4(Q.z, Q.w); \
        aLo.x += W * lo.x; aLo.y += W * lo.y; aLo.z += W * lo.z; aLo.w += W * lo.w; \
        aHi.x += W * hi.x; aHi.y += W * hi.y; aHi.z += W * hi.z; aHi.w += W * hi.w; }
        ACC(q0, w0) ACC(q1, w1) ACC(q2, w2) ACC(q3, w3)
        ACC(q4, w4) ACC(q5, w5) ACC(q6, w6) ACC(q7, w7)
#undef ACC
        ca = na; cb = nb;
    }
#undef WGT
    float4 bLo = bias4[2 * l8], bBhi = bias4[2 * l8 + 1];
    aLo.x += bLo.x; aLo.y += bLo.y; aLo.z += bLo.z; aLo.w += bLo.w;
    aHi.x += bBhi.x; aHi.y += bBhi.y; aHi.z += bBhi.z; aHi.w += bBhi.w;
    // LayerNorm over 64 features within the 8-lane octet
    float s = aLo.x + aLo.y + aLo.z + aLo.w + aHi.x + aHi.y + aHi.z + aHi.w;
#pragma unroll
    for (int o = 1; o <= 4; o <<= 1) s += __shfl_xor(s, o);
    float mu = s * (1.0f / 64.0f);
    float4 cLo = make_float4(aLo.x - mu, aLo.y - mu, aLo.z - mu, aLo.w - mu);
    float4 cHi = make_float4(aHi.x - mu, aHi.y - mu, aHi.z - mu, aHi.w - mu);
    float q2v = cLo.x * cLo.x + cLo.y * cLo.y + cLo.z * cLo.z + cLo.w * cLo.w
              + cHi.x * cHi.x + cHi.y * cHi.y + cHi.z * cHi.z + cHi.w * cHi.w;
#pragma unroll
    for (int o = 1; o <= 4; o <<= 1) q2v += __shfl_xor(q2v, o);
    float rs = rsqrtf(q2v * (1.0f / 64.0f) + 1e-5f);
    float4 gLo = gamma4[2 * l8], gHi = gamma4[2 * l8 + 1];
    float4 tLo = beta4[2 * l8],  tHi = beta4[2 * l8 + 1];
    float4 yLo = make_float4(cLo.x * rs * gLo.x + tLo.x, cLo.y * rs * gLo.y + tLo.y,
                             cLo.z * rs * gLo.z + tLo.z, cLo.w * rs * gLo.w + tLo.w);
    float4 yHi = make_float4(cHi.x * rs * gHi.x + tHi.x, cHi.y * rs * gHi.y + tHi.y,
                             cHi.z * rs * gHi.z + tHi.z, cHi.w * rs * gHi.w + tHi.w);
    float4 eLo = make_float4(yLo.x > 0.f ? yLo.x : 0.01f * yLo.x,
                             yLo.y > 0.f ? yLo.y : 0.01f * yLo.y,
                             yLo.z > 0.f ? yLo.z : 0.01f * yLo.z,
                             yLo.w > 0.f ? yLo.w : 0.01f * yLo.w);
    float4 eHi = make_float4(yHi.x > 0.f ? yHi.x : 0.01f * yHi.x,
                             yHi.y > 0.f ? yHi.y : 0.01f * yHi.y,
                             yHi.z > 0.f ? yHi.z : 0.01f * yHi.z,
                             yHi.w > 0.f ? yHi.w : 0.01f * yHi.w);
    if (!last) {
        uint4 o;
        o.x = (uint)f2bf(eLo.x) | ((uint)f2bf(eLo.y) << 16);
        o.y = (uint)f2bf(eLo.z) | ((uint)f2bf(eLo.w) << 16);
        o.z = (uint)f2bf(eHi.x) | ((uint)f2bf(eHi.y) << 16);
        o.w = (uint)f2bf(eHi.z) | ((uint)f2bf(eHi.w) << 16);
        next[(size_t)v * 8 + l8] = o;
    } else {
        uint4 u1 = c1[(size_t)v * 8 + l8];
        uint4 u2 = c2[(size_t)v * 8 + l8];
        uint4 u3 = c3[(size_t)v * 8 + l8];
        float4 p1 = bf4_to_f4(u1.x, u1.y), p1h = bf4_to_f4(u1.z, u1.w);
        float4 p2 = bf4_to_f4(u2.x, u2.y), p2h = bf4_to_f4(u2.z, u2.w);
        float4 p3 = bf4_to_f4(u3.x, u3.y), p3h = bf4_to_f4(u3.z, u3.w);
        float4 oLo, oHi;
        oLo.x = 0.5f * (p1.x + p2.x + p3.x + eLo.x);
        oLo.y = 0.5f * (p1.y + p2.y + p3.y + eLo.y);
        oLo.z = 0.5f * (p1.z + p2.z + p3.z + eLo.z);
        oLo.w = 0.5f * (p1.w + p2.w + p3.w + eLo.w);
        oHi.x = 0.5f * (p1h.x + p2h.x + p3h.x + eHi.x);
        oHi.y = 0.5f * (p1h.y + p2h.y + p3h.y + eHi.y);
        oHi.z = 0.5f * (p1h.z + p2h.z + p3h.z + eHi.z);
        oHi.w = 0.5f * (p1h.w + p2h.w + p3h.w + eHi.w);
        outp[(size_t)v * 16 + 2 * l8]     = oLo;
        outp[(size_t)v * 16 + 2 * l8 + 1] = oHi;
    }
}

// ---- launch -------------------------------------------------------------

extern "C" void kernel_launch(void* const* d_in, const int* in_sizes, int n_in,
                              void* d_out, int out_size, void* d_ws, size_t ws_size,
                              hipStream_t stream) {
    const float* x      = (const float*)d_in[0];
    const int*   ei     = (const int*)d_in[1];
    const int*   src    = ei;
    const int*   dst    = ei + NE;
    const int*   idx    = (const int*)d_in[2];
    const float* Ws     = (const float*)d_in[3];
    const float* bs     = (const float*)d_in[4];
    const float* gammas = (const float*)d_in[5];
    const float* betas  = (const float*)d_in[6];
    float* out = (float*)d_out;

    char* w = (char*)d_ws;
    auto alloc = [&](size_t bytes) -> char* {
        char* p = w;
        w += (bytes + 255) & ~(size_t)255;
        return p;
    };
    ushort* c[NL];
    for (int l = 0; l < NL; ++l) c[l] = (ushort*)alloc((size_t)NN * 64 * 2);
    ushort* xw    = (ushort*)alloc((size_t)NN * 64 * 2);
    int*   cnt    = (int*)alloc((size_t)NN * 4);
    int*   rowptr = (int*)alloc((size_t)(NN + 1) * 4);
    int*   rank   = (int*)alloc((size_t)NE * 4);
    float* dinv   = (float*)alloc((size_t)NN * 4);
    uint*  csr    = (uint*)alloc((size_t)CSR_CAP * 4);

    hipMemsetAsync(cnt, 0, (size_t)NN * 4, stream);
    hipMemsetAsync(c[0], 0, (size_t)NN * 64 * 2, stream);
    hipMemsetAsync(csr, 0, (size_t)CSR_CAP * 4, stream);

    count_edges_k<<<(NE + 255) / 256, 256, 0, stream>>>(dst, cnt, rank, NE);
    scan_all_k<<<1, 1024, 0, stream>>>(cnt, rowptr, dinv, NN);
    fill_scatter_k<<<3125 + 1563, 256, 0, stream>>>(src, dst, rank, rowptr, dinv, csr,
                                                    (const float4*)x, idx, (ushort4*)c[0]);

    int agrid = (NN + 31) / 32;   // 1563
    for (int l = 0; l < NL; ++l) {
        gemm64_k<<<NN / 16, 256, 0, stream>>>((const uint2*)c[l], Ws + (size_t)l * 64 * 64,
                                              xw);
        int last = (l == NL - 1);
        agg_ln_k<<<agrid, 256, 0, stream>>>((const uint4*)xw, rowptr, csr, dinv,
                                            (const float4*)(bs + l * 64),
                                            (const float4*)(gammas + l * 64),
                                            (const float4*)(betas + l * 64),
                                            last ? nullptr : (uint4*)c[l + 1],
                                            (const uint4*)c[1], (const uint4*)c[2],
                                            (const uint4*)c[3], (float4*)out, last);
    }
}

// Round 9
// 209.042 us; speedup vs baseline: 1.5373x; 1.5373x over previous
//
#include <hip/hip_runtime.h>
#include <hip/hip_fp16.h>

#define NN 50000
#define NP 25000
#define NE 800000
#define DD 64
#define NL 4
#define CSR_CAP (NE + 7 * NN + 16)   // padded segments + prefetch slack

// ---- helpers ------------------------------------------------------------

__device__ __forceinline__ ushort f2bf(float f) {
    unsigned u = __float_as_uint(f);
    unsigned r = (u + 0x7fffu + ((u >> 16) & 1u)) >> 16;   // RNE
    return (ushort)r;
}

__device__ __forceinline__ float4 bf4_to_f4(uint a, uint b) {
    float4 r;
    r.x = __uint_as_float(a << 16);
    r.y = __uint_as_float(a & 0xffff0000u);
    r.z = __uint_as_float(b << 16);
    r.w = __uint_as_float(b & 0xffff0000u);
    return r;
}

__device__ __forceinline__ float4 ld_bf16x4(const uint2* p) {
    uint2 q = *p;
    return bf4_to_f4(q.x, q.y);
}

// ---- CSR build ----------------------------------------------------------
// Pass 1: count in-degree AND record each edge's rank within its dst bucket.

__global__ void count_edges_k(const int* __restrict__ dst, int* __restrict__ cnt,
                              int* __restrict__ rank, int E) {
    int e = blockIdx.x * 256 + threadIdx.x;
    if (e < E) rank[e] = atomicAdd(&cnt[dst[e]], 1);
}

// Block-local exclusive scan of PADDED counts (multiple of 8 per segment).
__global__ void scan_local_k(const int* __restrict__ cnt, int* __restrict__ rowptr,
                             int* __restrict__ bsum, int n) {
    __shared__ int tmp[1024];
    int t = threadIdx.x;
    int i = blockIdx.x * 1024 + t;
    int v = (i < n) ? ((cnt[i] + 7) & ~7) : 0;
    tmp[t] = v;
    __syncthreads();
    for (int off = 1; off < 1024; off <<= 1) {
        int a = (t >= off) ? tmp[t - off] : 0;
        __syncthreads();
        tmp[t] += a;
        __syncthreads();
    }
    if (i < n) rowptr[i] = tmp[t] - v;      // block-local exclusive scan
    if (t == 1023) bsum[blockIdx.x] = tmp[1023];
}

__global__ void scan_sums_k(int* bsum, int nb, int* rowptr, int n) {
    int t = threadIdx.x;                    // 64 threads, nb <= 64
    int v = (t < nb) ? bsum[t] : 0;
    int s = v;
#pragma unroll
    for (int o = 1; o < 64; o <<= 1) {
        int u = __shfl_up(s, o);
        if (t >= o) s += u;
    }
    if (t < nb) bsum[t] = s - v;            // exclusive
    if (t == nb - 1) rowptr[n] = s;         // total
}

__global__ void finalize_k(int* __restrict__ rowptr, const int* __restrict__ bsum,
                           const int* __restrict__ cnt, float* __restrict__ dinv, int n) {
    int i = blockIdx.x * 1024 + threadIdx.x;
    if (i < n) {
        rowptr[i] += bsum[blockIdx.x];
        dinv[i] = rsqrtf((float)(cnt[i] + 1));   // +1 self loop; deg >= 1 always
    }
}

// csr entry: bits 0..15 = src index (NN < 65536), bits 16..31 = fp16 weight.
// Block range [0,3125): CSR fill (no atomics). [3125,4688): unpool scatter.
__global__ void fill_scatter_k(const int* __restrict__ src, const int* __restrict__ dst,
                               const int* __restrict__ rank, const int* __restrict__ rowptr,
                               const float* __restrict__ dinv, uint* __restrict__ csr,
                               const float4* __restrict__ x4, const int* __restrict__ idx,
                               ushort4* __restrict__ c0) {
    int b = blockIdx.x;
    if (b < 3125) {
        int e = b * 256 + threadIdx.x;   // 3125*256 == NE
        int s = src[e], d = dst[e];
        int p = rowptr[d] + rank[e];
        float w = dinv[s] * dinv[d];
        uint h = (uint)__half_as_ushort(__float2half_rn(w));
        csr[p] = (uint)s | (h << 16);
    } else {
        int i = (b - 3125) * 256 + threadIdx.x;   // NP*16 quads
        if (i >= NP * 16) return;
        int row = i >> 4, q = i & 15;
        float4 v = x4[i];
        ushort4 o;
        o.x = f2bf(v.x); o.y = f2bf(v.y); o.z = f2bf(v.z); o.w = f2bf(v.w);
        c0[(size_t)idx[row] * 16 + q] = o;
    }
}

// ---- GEMM: xw_bf16[50000x64] = cur_bf16[50000x64] @ W[64x64] ------------

__global__ void gemm64_k(const uint2* __restrict__ in2, const float* __restrict__ W,
                         ushort* __restrict__ out) {
    __shared__ float sW[64][64];     // 16 KB
    __shared__ float srow[16][64];   // 4 KB
    int t = threadIdx.x;             // 256 threads
    const float4* W4 = (const float4*)W;
    float4* sW4 = (float4*)sW;
#pragma unroll
    for (int j = 0; j < 4; ++j) sW4[t + 256 * j] = W4[t + 256 * j];
    int r0 = blockIdx.x * 16;
    float4 val = ld_bf16x4(in2 + (size_t)r0 * 16 + t);
    *(float4*)&srow[t >> 4][4 * (t & 15)] = val;
    __syncthreads();
    int r = t >> 4;            // 0..15
    int c4 = (t & 15) * 4;     // 0,4,...,60
    float ax = 0.f, ay = 0.f, az = 0.f, aw = 0.f;
#pragma unroll
    for (int k = 0; k < 64; ++k) {
        float a = srow[r][k];
        float4 w = *(const float4*)&sW[k][c4];
        ax += a * w.x; ay += a * w.y; az += a * w.z; aw += a * w.w;
    }
    ushort4 o;
    o.x = f2bf(ax); o.y = f2bf(ay); o.z = f2bf(az); o.w = f2bf(aw);
    *(ushort4*)&out[(size_t)(r0 + r) * 64 + c4] = o;
}

// ---- fused: aggregate(bf16 gather) + bias + LN + LeakyReLU --------------
// 8 nodes per wave (8-lane octets). Lane l8 holds features 8*l8..8*l8+7.
// Padded CSR: segments are multiples of 8 entries, 16B-aligned; pad entries
// are (src=0, w=0). 8 edges/iter from 2 uint4 loads, next iter's csr
// prefetched while gathers are in flight. No clamps, no tail logic.

__global__ void agg_ln_k(const uint4* __restrict__ xw4, const int* __restrict__ rowptr,
                         const uint* __restrict__ csr, const float* __restrict__ dinv,
                         const float4* __restrict__ bias4, const float4* __restrict__ gamma4,
                         const float4* __restrict__ beta4, uint4* next,
                         const uint4* c1, const uint4* c2, const uint4* c3,
                         float4* outp, int last) {
    int tid = threadIdx.x;
    int l8 = tid & 7;                       // feature octet-chunk 0..7
    int v = blockIdx.x * 32 + (tid >> 3);   // 32 nodes per 256-thread block
    if (v >= NN) return;
    const uint4* csrq = (const uint4*)csr;
    float dv = dinv[v];
    int jb = rowptr[v], je = rowptr[v + 1];   // both multiples of 8
    float4 aLo, aHi;
    {
        uint4 q = xw4[(size_t)v * 8 + l8];   // self loop
        float4 lo = bf4_to_f4(q.x, q.y), hi = bf4_to_f4(q.z, q.w);
        float s = dv * dv;
        aLo.x = s * lo.x; aLo.y = s * lo.y; aLo.z = s * lo.z; aLo.w = s * lo.w;
        aHi.x = s * hi.x; aHi.y = s * hi.y; aHi.z = s * hi.z; aHi.w = s * hi.w;
    }
    uint4 ca = csrq[jb >> 2];        // safe: buffer has slack
    uint4 cb = csrq[(jb >> 2) + 1];
#define WGT(E)  __half2float(__ushort_as_half((ushort)((E) >> 16)))
    for (int j = jb; j < je; j += 8) {
        uint4 na = csrq[(j >> 2) + 2];   // prefetch next 8 entries
        uint4 nb = csrq[(j >> 2) + 3];
        uint4 q0 = xw4[(size_t)(ca.x & 0xffffu) * 8 + l8];
        uint4 q1 = xw4[(size_t)(ca.y & 0xffffu) * 8 + l8];
        uint4 q2 = xw4[(size_t)(ca.z & 0xffffu) * 8 + l8];
        uint4 q3 = xw4[(size_t)(ca.w & 0xffffu) * 8 + l8];
        uint4 q4 = xw4[(size_t)(cb.x & 0xffffu) * 8 + l8];
        uint4 q5 = xw4[(size_t)(cb.y & 0xffffu) * 8 + l8];
        uint4 q6 = xw4[(size_t)(cb.z & 0xffffu) * 8 + l8];
        uint4 q7 = xw4[(size_t)(cb.w & 0xffffu) * 8 + l8];
        float w0 = WGT(ca.x), w1 = WGT(ca.y), w2 = WGT(ca.z), w3 = WGT(ca.w);
        float w4 = WGT(cb.x), w5 = WGT(cb.y), w6 = WGT(cb.z), w7 = WGT(cb.w);
#define ACC(Q, W) { \
        float4 lo = bf4_to_f4(Q.x, Q.y), hi = bf4_to_f4(Q.z, Q.w); \
        aLo.x += W * lo.x; aLo.y += W * lo.y; aLo.z += W * lo.z; aLo.w += W * lo.w; \
        aHi.x += W * hi.x; aHi.y += W * hi.y; aHi.z += W * hi.z; aHi.w += W * hi.w; }
        ACC(q0, w0) ACC(q1, w1) ACC(q2, w2) ACC(q3, w3)
        ACC(q4, w4) ACC(q5, w5) ACC(q6, w6) ACC(q7, w7)
#undef ACC
        ca = na; cb = nb;
    }
#undef WGT
    float4 bLo = bias4[2 * l8], bBhi = bias4[2 * l8 + 1];
    aLo.x += bLo.x; aLo.y += bLo.y; aLo.z += bLo.z; aLo.w += bLo.w;
    aHi.x += bBhi.x; aHi.y += bBhi.y; aHi.z += bBhi.z; aHi.w += bBhi.w;
    // LayerNorm over 64 features within the 8-lane octet
    float s = aLo.x + aLo.y + aLo.z + aLo.w + aHi.x + aHi.y + aHi.z + aHi.w;
#pragma unroll
    for (int o = 1; o <= 4; o <<= 1) s += __shfl_xor(s, o);
    float mu = s * (1.0f / 64.0f);
    float4 cLo = make_float4(aLo.x - mu, aLo.y - mu, aLo.z - mu, aLo.w - mu);
    float4 cHi = make_float4(aHi.x - mu, aHi.y - mu, aHi.z - mu, aHi.w - mu);
    float q2v = cLo.x * cLo.x + cLo.y * cLo.y + cLo.z * cLo.z + cLo.w * cLo.w
              + cHi.x * cHi.x + cHi.y * cHi.y + cHi.z * cHi.z + cHi.w * cHi.w;
#pragma unroll
    for (int o = 1; o <= 4; o <<= 1) q2v += __shfl_xor(q2v, o);
    float rs = rsqrtf(q2v * (1.0f / 64.0f) + 1e-5f);
    float4 gLo = gamma4[2 * l8], gHi = gamma4[2 * l8 + 1];
    float4 tLo = beta4[2 * l8],  tHi = beta4[2 * l8 + 1];
    float4 yLo = make_float4(cLo.x * rs * gLo.x + tLo.x, cLo.y * rs * gLo.y + tLo.y,
                             cLo.z * rs * gLo.z + tLo.z, cLo.w * rs * gLo.w + tLo.w);
    float4 yHi = make_float4(cHi.x * rs * gHi.x + tHi.x, cHi.y * rs * gHi.y + tHi.y,
                             cHi.z * rs * gHi.z + tHi.z, cHi.w * rs * gHi.w + tHi.w);
    float4 eLo = make_float4(yLo.x > 0.f ? yLo.x : 0.01f * yLo.x,
                             yLo.y > 0.f ? yLo.y : 0.01f * yLo.y,
                             yLo.z > 0.f ? yLo.z : 0.01f * yLo.z,
                             yLo.w > 0.f ? yLo.w : 0.01f * yLo.w);
    float4 eHi = make_float4(yHi.x > 0.f ? yHi.x : 0.01f * yHi.x,
                             yHi.y > 0.f ? yHi.y : 0.01f * yHi.y,
                             yHi.z > 0.f ? yHi.z : 0.01f * yHi.z,
                             yHi.w > 0.f ? yHi.w : 0.01f * yHi.w);
    if (!last) {
        uint4 o;
        o.x = (uint)f2bf(eLo.x) | ((uint)f2bf(eLo.y) << 16);
        o.y = (uint)f2bf(eLo.z) | ((uint)f2bf(eLo.w) << 16);
        o.z = (uint)f2bf(eHi.x) | ((uint)f2bf(eHi.y) << 16);
        o.w = (uint)f2bf(eHi.z) | ((uint)f2bf(eHi.w) << 16);
        next[(size_t)v * 8 + l8] = o;
    } else {
        uint4 u1 = c1[(size_t)v * 8 + l8];
        uint4 u2 = c2[(size_t)v * 8 + l8];
        uint4 u3 = c3[(size_t)v * 8 + l8];
        float4 p1 = bf4_to_f4(u1.x, u1.y), p1h = bf4_to_f4(u1.z, u1.w);
        float4 p2 = bf4_to_f4(u2.x, u2.y), p2h = bf4_to_f4(u2.z, u2.w);
        float4 p3 = bf4_to_f4(u3.x, u3.y), p3h = bf4_to_f4(u3.z, u3.w);
        float4 oLo, oHi;
        oLo.x = 0.5f * (p1.x + p2.x + p3.x + eLo.x);
        oLo.y = 0.5f * (p1.y + p2.y + p3.y + eLo.y);
        oLo.z = 0.5f * (p1.z + p2.z + p3.z + eLo.z);
        oLo.w = 0.5f * (p1.w + p2.w + p3.w + eLo.w);
        oHi.x = 0.5f * (p1h.x + p2h.x + p3h.x + eHi.x);
        oHi.y = 0.5f * (p1h.y + p2h.y + p3h.y + eHi.y);
        oHi.z = 0.5f * (p1h.z + p2h.z + p3h.z + eHi.z);
        oHi.w = 0.5f * (p1h.w + p2h.w + p3h.w + eHi.w);
        outp[(size_t)v * 16 + 2 * l8]     = oLo;
        outp[(size_t)v * 16 + 2 * l8 + 1] = oHi;
    }
}

// ---- launch -------------------------------------------------------------

extern "C" void kernel_launch(void* const* d_in, const int* in_sizes, int n_in,
                              void* d_out, int out_size, void* d_ws, size_t ws_size,
                              hipStream_t stream) {
    const float* x      = (const float*)d_in[0];
    const int*   ei     = (const int*)d_in[1];
    const int*   src    = ei;
    const int*   dst    = ei + NE;
    const int*   idx    = (const int*)d_in[2];
    const float* Ws     = (const float*)d_in[3];
    const float* bs     = (const float*)d_in[4];
    const float* gammas = (const float*)d_in[5];
    const float* betas  = (const float*)d_in[6];
    float* out = (float*)d_out;

    char* w = (char*)d_ws;
    auto alloc = [&](size_t bytes) -> char* {
        char* p = w;
        w += (bytes + 255) & ~(size_t)255;
        return p;
    };
    ushort* c[NL];
    for (int l = 0; l < NL; ++l) c[l] = (ushort*)alloc((size_t)NN * 64 * 2);
    ushort* xw    = (ushort*)alloc((size_t)NN * 64 * 2);
    int*   cnt    = (int*)alloc((size_t)NN * 4);
    int*   rowptr = (int*)alloc((size_t)(NN + 1) * 4);
    int*   rank   = (int*)alloc((size_t)NE * 4);
    float* dinv   = (float*)alloc((size_t)NN * 4);
    int*   bsum   = (int*)alloc(64 * 4);
    uint*  csr    = (uint*)alloc((size_t)CSR_CAP * 4);

    hipMemsetAsync(cnt, 0, (size_t)NN * 4, stream);
    hipMemsetAsync(c[0], 0, (size_t)NN * 64 * 2, stream);
    hipMemsetAsync(csr, 0, (size_t)CSR_CAP * 4, stream);

    count_edges_k<<<(NE + 255) / 256, 256, 0, stream>>>(dst, cnt, rank, NE);
    int nb = (NN + 1023) / 1024;   // 49
    scan_local_k<<<nb, 1024, 0, stream>>>(cnt, rowptr, bsum, NN);
    scan_sums_k<<<1, 64, 0, stream>>>(bsum, nb, rowptr, NN);
    finalize_k<<<nb, 1024, 0, stream>>>(rowptr, bsum, cnt, dinv, NN);
    fill_scatter_k<<<3125 + 1563, 256, 0, stream>>>(src, dst, rank, rowptr, dinv, csr,
                                                    (const float4*)x, idx, (ushort4*)c[0]);

    int agrid = (NN + 31) / 32;   // 1563
    for (int l = 0; l < NL; ++l) {
        gemm64_k<<<NN / 16, 256, 0, stream>>>((const uint2*)c[l], Ws + (size_t)l * 64 * 64,
                                              xw);
        int last = (l == NL - 1);
        agg_ln_k<<<agrid, 256, 0, stream>>>((const uint4*)xw, rowptr, csr, dinv,
                                            (const float4*)(bs + l * 64),
                                            (const float4*)(gammas + l * 64),
                                            (const float4*)(betas + l * 64),
                                            last ? nullptr : (uint4*)c[l + 1],
                                            (const uint4*)c[1], (const uint4*)c[2],
                                            (const uint4*)c[3], (float4*)out, last);
    }
}